// Round 4
// baseline (172.132 us; speedup 1.0000x reference)
//
#include <hip/hip_runtime.h>
#include <math.h>

#define B_    32
#define H_    512
#define W_    512
#define NBINS 256
#define NT    254
#define HW_   (H_ * W_)

// ws layout — every slot written unconditionally each replay.
// Bulk kernel uses ONLY kernel-boundary coherence (R1 lesson: per-block
// __threadfence in the bulk kernel = ~1 L2 writeback per block = +120 µs).
// The one-shot ticket (fence + atomicAdd + agent loads, no spin) lives only
// in the 32-block tail (R0-validated).
// R4: bulk grid is 2048 blocks (16 rows x 256 cols each) — R3 counters showed
// k_main_p latency-bound with all pipes idle at 16 waves/CU; this doubles
// resident waves to 32/CU.
//   [0       .. 2097152)  int   hist_p[2048][256]   per-block Otsu-hist partial
//   [2097152 .. 4194304)  int   g0_p[2048][256]     per-block q-bucket count
//   [4194304 .. 6291456)  float g1_p[2048][256]     per-block q-bucket sum-p
//   [6291456 .. 6299648)  float p2_p[2048]          per-block sum p^2
//   [6299648 .. 6299776)  float totf[32]            per-batch mask count
//   [6299776 .. 6299904)  float lp[32]              per-batch loss
//   [6299904 .. 6299908)  int   gt                  global ticket (zeroed by k_main_p)
#define OFF_G0   2097152
#define OFF_G1   4194304
#define OFF_P2   6291456
#define OFF_TOTF 6299648
#define OFF_LP   6299776
#define OFF_GT   6299904
#define WS_NEED  6299908

__device__ __forceinline__ float max5(float a, float b, float c, float d, float e) {
    return fmaxf(fmaxf(fmaxf(a, b), fmaxf(c, d)), e);
}
__device__ __forceinline__ float4 fmax4(float4 a, float4 b) {
    return make_float4(fmaxf(a.x, b.x), fmaxf(a.y, b.y),
                       fmaxf(a.z, b.z), fmaxf(a.w, b.w));
}
__device__ __forceinline__ float2 fmax2(float2 a, float2 b) {
    return make_float2(fmaxf(a.x, b.x), fmaxf(a.y, b.y));
}
__device__ __forceinline__ int bin_of(float im) {
    float v = im * 255.0f;                  // reference: v = imgs*255
    float u = v * (256.0f / 255.0f);        // reference: v*(NBINS/255.0) in f32
    int bin = (int)floorf(u);
    return bin < 0 ? 0 : (bin > NBINS - 1 ? NBINS - 1 : bin);
}

// Dilated-mask (5x5 max > 0) for 4 rows x 4 cols/lane over a 256-col strip.
// Same window math as the R7-R12-validated dilate4, but one float4/lane and
// explicit 2-float halo loads at the interior column seam (lanes 0 / 63).
// Outside-image halo stays 0 (cb==0 or cb+256==W_), matching zero padding.
__device__ __forceinline__ void dilate4c(const float* __restrict__ lab,
                                         int rbase, int cb, int lane,
                                         unsigned mrow[4]) {
    float4 A[4];
    float2 Lh[4], Rh[4];
#pragma unroll
    for (int r = 0; r < 4; ++r) {
        A[r]  = make_float4(0.f, 0.f, 0.f, 0.f);
        Lh[r] = make_float2(0.f, 0.f);
        Rh[r] = make_float2(0.f, 0.f);
    }
    const int  c0    = cb + lane * 4;
    const bool edgeL = (lane == 0)  && (cb > 0);
    const bool edgeR = (lane == 63) && (cb + 256 < W_);
#pragma unroll
    for (int k = 0; k < 8; ++k) {
        int gr = rbase - 2 + k;
        float4 la = make_float4(0.f, 0.f, 0.f, 0.f);
        float2 lf = make_float2(0.f, 0.f), rf = lf;
        if ((unsigned)gr < (unsigned)H_) {
            la = *(const float4*)(lab + gr * W_ + c0);
            if (edgeL) lf = *(const float2*)(lab + gr * W_ + cb - 2);
            if (edgeR) rf = *(const float2*)(lab + gr * W_ + cb + 256);
        }
#pragma unroll
        for (int r = 0; r < 4; ++r)
            if (k >= r && k <= r + 4) {
                A[r]  = fmax4(A[r], la);
                Lh[r] = fmax2(Lh[r], lf);
                Rh[r] = fmax2(Rh[r], rf);
            }
    }
#pragma unroll
    for (int r = 0; r < 4; ++r) {
        float l2 = __shfl_up(A[r].z, 1);
        float l1 = __shfl_up(A[r].w, 1);
        float r1 = __shfl_down(A[r].x, 1);
        float r2 = __shfl_down(A[r].y, 1);
        if (lane == 0)  { l2 = Lh[r].x; l1 = Lh[r].y; }
        if (lane == 63) { r1 = Rh[r].x; r2 = Rh[r].y; }
        float e[8] = { l2, l1, A[r].x, A[r].y, A[r].z, A[r].w, r1, r2 };
        unsigned m = 0;
#pragma unroll
        for (int c = 0; c < 4; ++c)
            if (max5(e[c], e[c+1], e[c+2], e[c+3], e[c+4]) > 0.f) m |= 1u << c;
        mrow[r] = m;
    }
}

// Per-pixel accumulate (validated R5-R12): Otsu hist + exact q-bucket + sum p^2.
__device__ __forceinline__ void px_acc(unsigned m, unsigned bit, float im, float p,
                                       int* s_hist, int* s_g0, float* s_g1,
                                       const float* s_thr, float& p2a) {
    if (m & bit) {
        atomicAdd(&s_hist[bin_of(im)], 1);
        int q0 = (int)(im * 255.0f);
        if (q0 > 254) q0 = 254;
        int q = q0;
        if (q0 < 254 && im >= s_thr[q0 + 1]) q = q0 + 1;
        else if (q0 > 0 && im < s_thr[q0])   q = q0 - 1;
        atomicAdd(&s_g0[q], 1);
        atomicAdd(&s_g1[q], p);
        p2a += p * p;
    }
}

// ---------------------------------------------------------------------------
// Kernel 1: dense single pass. 2048 blocks (16 rows x 256 cols), 8 blocks/CU
// = 32 waves/CU (R3: 16 waves/CU was latency-starved — all pipes <18%).
// No fences/tickets here — kernel-boundary coherence only (R1 lesson).
// ---------------------------------------------------------------------------
__global__ __launch_bounds__(256, 8) void k_main_p(const float* __restrict__ labels,
                                                   const float* __restrict__ images,
                                                   const float* __restrict__ preds,
                                                   int* __restrict__ hist_p,
                                                   int* __restrict__ g0_p,
                                                   float* __restrict__ g1_p,
                                                   float* __restrict__ p2_p,
                                                   int* __restrict__ gt) {
    __shared__ int   s_hist[NBINS];
    __shared__ int   s_g0[NBINS];
    __shared__ float s_g1[NBINS];
    __shared__ float s_thr[NBINS];
    __shared__ float s_red[256];

    const int tid   = threadIdx.x;
    const int lane  = tid & 63;
    const int w     = tid >> 6;
    const int bx    = blockIdx.x;           // 0..63 = band*2 + half
    const int band  = bx >> 1;              // 0..31 (16-row bands)
    const int half  = bx & 1;               // 0..1  (256-col halves)
    const int b     = blockIdx.y;           // 0..31
    const int slot  = b * 64 + bx;
    const int rbase = band * 16 + w * 4;
    const int cb    = half * 256;
    const int c0    = cb + lane * 4;
    const float* lab = labels + (size_t)b * HW_;
    const float* img = images + (size_t)b * HW_;
    const float* prd = preds  + (size_t)b * HW_;

    if (bx == 0 && b == 0 && tid == 0) *gt = 0;   // boundary-ordered reset

    s_hist[tid] = 0;
    s_g0[tid]   = 0;
    s_g1[tid]   = 0.0f;
    s_thr[tid]  = (float)tid / 255.0f;
    __syncthreads();

    unsigned mrow[4];
    dilate4c(lab, rbase, cb, lane, mrow);

    float p2a = 0.0f;
#pragma unroll
    for (int r = 0; r < 4; ++r) {
        unsigned m = mrow[r];
        size_t off = (size_t)(rbase + r) * W_ + c0;
        // dense unconditional loads (sparse-load MLP collapse measured R4)
        float4 iv = *(const float4*)(img + off);
        float4 pv = *(const float4*)(prd + off);
        px_acc(m, 1u, iv.x, pv.x, s_hist, s_g0, s_g1, s_thr, p2a);
        px_acc(m, 2u, iv.y, pv.y, s_hist, s_g0, s_g1, s_thr, p2a);
        px_acc(m, 4u, iv.z, pv.z, s_hist, s_g0, s_g1, s_thr, p2a);
        px_acc(m, 8u, iv.w, pv.w, s_hist, s_g0, s_g1, s_thr, p2a);
    }

    s_red[tid] = p2a;
    __syncthreads();
    // plain stores to this block's own slot (every slot written -> poison-safe)
    hist_p[(slot << 8) + tid] = s_hist[tid];
    g0_p  [(slot << 8) + tid] = s_g0[tid];
    g1_p  [(slot << 8) + tid] = s_g1[tid];
    for (int off = 128; off > 0; off >>= 1) {
        if (tid < off) s_red[tid] += s_red[tid + off];
        __syncthreads();
    }
    if (tid == 0) p2_p[slot] = s_red[0];
}

// ---------------------------------------------------------------------------
// Kernel 2: merged search + eval, 32 blocks x 1024 threads (16 waves).
// Bit-safe parallel phases: hist reduce (int, order-free) split 4-way;
// 254x254 argmax (u64 max, order-free) split over 4 row-groups.
// Order-sensitive float/f64 phases verbatim from validated code, tid<256.
// ---------------------------------------------------------------------------
__global__ __launch_bounds__(1024) void k_tail(const int* __restrict__ hist_p,
                                               const int* __restrict__ g0_p,
                                               const float* __restrict__ g1_p,
                                               const float* __restrict__ p2_p,
                                               float* __restrict__ totf,
                                               float* __restrict__ lp,
                                               int* __restrict__ gt,
                                               float* __restrict__ out) {
    __shared__ float  sA[NBINS];
    __shared__ float  sB[NBINS];
    __shared__ float  sT0[NBINS];
    __shared__ float  sT2[NBINS];
    __shared__ float  sP[NBINS];
    __shared__ float  sQ[NBINS];
    __shared__ int    s_int[1024];
    __shared__ unsigned long long s_pack[1024];
    __shared__ double sD0[256];
    __shared__ double sD1[256];
    __shared__ double s_res[4];

    const int tid = threadIdx.x;
    const int b   = blockIdx.x;
    const float s = 1e-8f;
    const int bin = tid & 255;          // 0..255
    const int grp = tid >> 8;           // 0..3

    // ---- histogram reduce: 64 band-partials -> bin, 4-way split (exact) --
    {
        const int* hp = hist_p + ((b * 64 + grp * 16) << 8) + bin;
        int hp16 = 0;
#pragma unroll
        for (int j = 0; j < 16; ++j) hp16 += hp[j << 8];
        s_int[tid] = hp16;
    }
    __syncthreads();
    int h = 0;
    if (tid < 256)
        h = s_int[tid] + s_int[tid + 256] + s_int[tid + 512] + s_int[tid + 768];
    __syncthreads();                    // all reads done before overwrite
    if (tid < 256) s_int[tid] = h;
    __syncthreads();
    for (int off = 128; off > 0; off >>= 1) {   // exact: integer counts
        if (tid < off) s_int[tid] += s_int[tid + off];
        __syncthreads();
    }
    const float ftot = (float)s_int[0];
    __syncthreads();

    if (tid < 256) {
        float pv = (float)h / ftot;
        sP[tid] = pv;
        sQ[tid] = pv * (float)tid;
    }
    __syncthreads();

    if (tid == 0) {                  // sequential fold == reference cumsum order
        float ch = 0.0f, cm = 0.0f;
#pragma unroll 8
        for (int i = 0; i < NBINS; ++i) {
            ch += sP[i];
            cm += sQ[i];
            sA[i] = ch;
            sB[i] = cm;
        }
    }
    __syncthreads();

    const float tm = sB[NBINS - 1];
    if (tid < NT) {
        float w0 = sA[tid];
        float mean0 = sB[tid] / (w0 + s);
        float d0 = mean0 - tm;
        sT0[tid] = w0 * (d0 * d0);
        float cb = sA[tid];
        float w2 = 1.0f - cb;
        float mean2 = (tm - sB[tid]) / (w2 + s);
        float d2 = mean2 - tm;
        sT2[tid] = w2 * (d2 * d2);
    }
    __syncthreads();

    // ---- 254x254 argmax: col = tid&255, rows split over 4 groups ---------
    // u64 max is order-independent -> bit-identical to the serial version.
    unsigned long long best = 0ull;
    if (bin < NT) {
        const float cb  = sA[bin];
        const float m1v = sB[bin];
        const float w2  = 1.0f - cb;
        const float t2v = sT2[bin];
        const int   i0  = grp * 64;
#pragma unroll 8
        for (int il = 0; il < 64; ++il) {
            int i = i0 + il;
            if (i >= NT) break;
            float w0 = sA[i];
            float w1 = cb - w0;
            float mean1 = (m1v - sB[i]) / (w1 + s);
            float d1 = mean1 - tm;
            float bv = (sT0[i] + w1 * (d1 * d1)) + t2v;
            bool ok = (w0 > 0.f) && (w1 > 0.f) && (w2 > 0.f);
            bv = ok ? bv : 0.0f;
            unsigned k = (unsigned)(i * NT + bin);
            // bv >= 0: float-bit order == value order; ~k => first-max tie-break
            unsigned long long pk =
                ((unsigned long long)__float_as_uint(bv) << 32) | (0xFFFFFFFFu - k);
            best = pk > best ? pk : best;
        }
    }
    s_pack[tid] = best;
    __syncthreads();
    for (int off = 512; off > 0; off >>= 1) {
        if (tid < off) {
            unsigned long long o = s_pack[tid + off];
            if (o > s_pack[tid]) s_pack[tid] = o;
        }
        __syncthreads();
    }
    const int am = (int)(0xFFFFFFFFu - (unsigned)(s_pack[0] & 0xFFFFFFFFull));
    const int v  = am / NT + 1;             // im >= t1  <=>  q >= v
    const int wq = am % NT + 1;             // im >= t2  <=>  q >= wq

    // ---- reduce g0/g1 partials (sequential j order preserved for gg) -----
    int   gc = 0;
    float gg = 0.0f;
    if (tid < 256) {
        const int*   gp  = g0_p + ((b * 64) << 8) + tid;
        const float* gfp = g1_p + ((b * 64) << 8) + tid;
#pragma unroll 8
        for (int j = 0; j < 64; ++j) { gc += gp[j << 8]; gg += gfp[j << 8]; }
    }

    // ---- f64 suffix sums S0/S1 at v and wq (validated, 256-tree verbatim) -
    if (tid < 256) {
        sD0[tid] = (tid >= v) ? (double)gc : 0.0;
        sD1[tid] = (tid >= v) ? (double)gg : 0.0;
    }
    __syncthreads();
    for (int off = 128; off > 0; off >>= 1) {
        if (tid < off) { sD0[tid] += sD0[tid + off]; sD1[tid] += sD1[tid + off]; }
        __syncthreads();
    }
    if (tid == 0) { s_res[0] = sD0[0]; s_res[1] = sD1[0]; }
    __syncthreads();

    if (tid < 256) {
        sD0[tid] = (tid >= wq) ? (double)gc : 0.0;
        sD1[tid] = (tid >= wq) ? (double)gg : 0.0;
    }
    __syncthreads();
    for (int off = 128; off > 0; off >>= 1) {
        if (tid < off) { sD0[tid] += sD0[tid + off]; sD1[tid] += sD1[tid + off]; }
        __syncthreads();
    }
    if (tid == 0) { s_res[2] = sD0[0]; s_res[3] = sD1[0]; }
    __syncthreads();

    // ---- p2 partial reduce (64 values, 256-tree) -------------------------
    if (tid < 256)
        sD0[tid] = (tid < 64) ? (double)p2_p[b * 64 + tid] : 0.0;
    __syncthreads();
    for (int off = 128; off > 0; off >>= 1) {
        if (tid < off) sD0[tid] += sD0[tid + off];
        __syncthreads();
    }

    if (tid == 0) {
        double S0v = s_res[0], S1v = s_res[1];
        double S0w = s_res[2], S1w = s_res[3];
        double c05 = (v <= wq) ? (S0v - S0w) : 0.0;
        double s05 = (v <= wq) ? (S1v - S1w) : 0.0;
        // sum (ci-p)^2 = |A| - 2*S1(A) + 0.25*|B\A| - S1(B\A) + sum p^2
        double sqd = S0w - 2.0 * S1w + 0.25 * c05 - s05 + sD0[0];
        float smv = ftot + 1e-8f;
        float lpv = (smv > 1e-8f) ? (float)sqd / smv : 0.0f;
        __hip_atomic_store(&lp[b], lpv, __ATOMIC_RELEASE, __HIP_MEMORY_SCOPE_AGENT);
        __hip_atomic_store(&totf[b], ftot, __ATOMIC_RELEASE, __HIP_MEMORY_SCOPE_AGENT);
        __threadfence();
        int t = atomicAdd(gt, 1);           // one-shot, no spin (R0-validated)
        if (t == B_ - 1) {                  // last block: all lp[]/totf[] published
            __threadfence();
            float sum = 0.0f;
            int   cnt = 0;
            for (int bb = 0; bb < B_; ++bb) {   // linear order == reference
                float tt = __hip_atomic_load(&totf[bb], __ATOMIC_RELAXED,
                                             __HIP_MEMORY_SCOPE_AGENT);
                float ll = __hip_atomic_load(&lp[bb], __ATOMIC_RELAXED,
                                             __HIP_MEMORY_SCOPE_AGENT);
                if (tt + 1e-8f > 1e-8f) { sum += ll; cnt += 1; }
            }
            out[0] = cnt > 0 ? sum / fmaxf((float)cnt, 1.0f) : 0.0f;
        }
    }
}

extern "C" void kernel_launch(void* const* d_in, const int* in_sizes, int n_in,
                              void* d_out, int out_size, void* d_ws, size_t ws_size,
                              hipStream_t stream) {
    const float* preds  = (const float*)d_in[0];
    const float* labels = (const float*)d_in[1];
    const float* images = (const float*)d_in[2];
    float* out = (float*)d_out;
    char* ws = (char*)d_ws;
    if (ws_size < (size_t)WS_NEED) return;  // harness ws is ~268 MB; never hit

    int*   hist_p = (int*)ws;
    int*   g0_p   = (int*)(ws + OFF_G0);
    float* g1_p   = (float*)(ws + OFF_G1);
    float* p2_p   = (float*)(ws + OFF_P2);
    float* totf   = (float*)(ws + OFF_TOTF);
    float* lp     = (float*)(ws + OFF_LP);
    int*   gt     = (int*)(ws + OFF_GT);

    k_main_p<<<dim3(64, B_), 256, 0, stream>>>(labels, images, preds,
                                               hist_p, g0_p, g1_p, p2_p, gt);
    k_tail<<<B_, 1024, 0, stream>>>(hist_p, g0_p, g1_p, p2_p,
                                    totf, lp, gt, out);
}

// Round 5
// 146.769 us; speedup vs baseline: 1.1728x; 1.1728x over previous
//
#include <hip/hip_runtime.h>
#include <math.h>

#define B_    32
#define H_    512
#define W_    512
#define NBINS 256
#define NT    254
#define HW_   (H_ * W_)

// ws layout — every slot written unconditionally each replay.
// Bulk kernel uses ONLY kernel-boundary coherence (R1 lesson: per-block
// __threadfence in the bulk kernel = +120 µs). One-shot ticket lives only in
// the 32-block tail (R0-validated).
// R5: bulk kernel back to 1024 partial slots (R4 lesson: 2048 slots doubled
// HBM traffic, +12 µs) but 512 threads/block -> 32 waves/CU at R3 traffic.
//   [0       .. 1048576)  int   hist_p[1024][256]   per-block Otsu-hist partial
//   [1048576 .. 2097152)  int   g0_p[1024][256]     per-block q-bucket count
//   [2097152 .. 3145728)  float g1_p[1024][256]     per-block q-bucket sum-p
//   [3145728 .. 3149824)  float p2_p[1024]          per-block sum p^2
//   [3149824 .. 3149952)  float totf[32]            per-batch mask count
//   [3149952 .. 3150080)  float lp[32]              per-batch loss
//   [3150080 .. 3150084)  int   gt                  global ticket (zeroed by k_main_p)
#define OFF_G0   1048576
#define OFF_G1   2097152
#define OFF_P2   3145728
#define OFF_TOTF 3149824
#define OFF_LP   3149952
#define OFF_GT   3150080
#define WS_NEED  3150084

__device__ __forceinline__ float max5(float a, float b, float c, float d, float e) {
    return fmaxf(fmaxf(fmaxf(a, b), fmaxf(c, d)), e);
}
__device__ __forceinline__ float4 fmax4(float4 a, float4 b) {
    return make_float4(fmaxf(a.x, b.x), fmaxf(a.y, b.y),
                       fmaxf(a.z, b.z), fmaxf(a.w, b.w));
}
__device__ __forceinline__ float2 fmax2(float2 a, float2 b) {
    return make_float2(fmaxf(a.x, b.x), fmaxf(a.y, b.y));
}
__device__ __forceinline__ int bin_of(float im) {
    float v = im * 255.0f;                  // reference: v = imgs*255
    float u = v * (256.0f / 255.0f);        // reference: v*(NBINS/255.0) in f32
    int bin = (int)floorf(u);
    return bin < 0 ? 0 : (bin > NBINS - 1 ? NBINS - 1 : bin);
}

// Dilated-mask (5x5 max > 0) for 4 rows x 4 cols/lane over a 256-col strip.
// Window math identical to the R7-R12-validated dilate4; halo via 2-float
// loads at the interior column seam (lanes 0 / 63). Outside-image halo = 0.
// Validated in R4 (absmax 0.0).
__device__ __forceinline__ void dilate4c(const float* __restrict__ lab,
                                         int rbase, int cb, int lane,
                                         unsigned mrow[4]) {
    float4 A[4];
    float2 Lh[4], Rh[4];
#pragma unroll
    for (int r = 0; r < 4; ++r) {
        A[r]  = make_float4(0.f, 0.f, 0.f, 0.f);
        Lh[r] = make_float2(0.f, 0.f);
        Rh[r] = make_float2(0.f, 0.f);
    }
    const int  c0    = cb + lane * 4;
    const bool edgeL = (lane == 0)  && (cb > 0);
    const bool edgeR = (lane == 63) && (cb + 256 < W_);
#pragma unroll
    for (int k = 0; k < 8; ++k) {
        int gr = rbase - 2 + k;
        float4 la = make_float4(0.f, 0.f, 0.f, 0.f);
        float2 lf = make_float2(0.f, 0.f), rf = lf;
        if ((unsigned)gr < (unsigned)H_) {
            la = *(const float4*)(lab + gr * W_ + c0);
            if (edgeL) lf = *(const float2*)(lab + gr * W_ + cb - 2);
            if (edgeR) rf = *(const float2*)(lab + gr * W_ + cb + 256);
        }
#pragma unroll
        for (int r = 0; r < 4; ++r)
            if (k >= r && k <= r + 4) {
                A[r]  = fmax4(A[r], la);
                Lh[r] = fmax2(Lh[r], lf);
                Rh[r] = fmax2(Rh[r], rf);
            }
    }
#pragma unroll
    for (int r = 0; r < 4; ++r) {
        float l2 = __shfl_up(A[r].z, 1);
        float l1 = __shfl_up(A[r].w, 1);
        float r1 = __shfl_down(A[r].x, 1);
        float r2 = __shfl_down(A[r].y, 1);
        if (lane == 0)  { l2 = Lh[r].x; l1 = Lh[r].y; }
        if (lane == 63) { r1 = Rh[r].x; r2 = Rh[r].y; }
        float e[8] = { l2, l1, A[r].x, A[r].y, A[r].z, A[r].w, r1, r2 };
        unsigned m = 0;
#pragma unroll
        for (int c = 0; c < 4; ++c)
            if (max5(e[c], e[c+1], e[c+2], e[c+3], e[c+4]) > 0.f) m |= 1u << c;
        mrow[r] = m;
    }
}

// Per-pixel accumulate (validated R5-R12): Otsu hist + exact q-bucket + sum p^2.
__device__ __forceinline__ void px_acc(unsigned m, unsigned bit, float im, float p,
                                       int* s_hist, int* s_g0, float* s_g1,
                                       const float* s_thr, float& p2a) {
    if (m & bit) {
        atomicAdd(&s_hist[bin_of(im)], 1);
        int q0 = (int)(im * 255.0f);
        if (q0 > 254) q0 = 254;
        int q = q0;
        if (q0 < 254 && im >= s_thr[q0 + 1]) q = q0 + 1;
        else if (q0 > 0 && im < s_thr[q0])   q = q0 - 1;
        atomicAdd(&s_g0[q], 1);
        atomicAdd(&s_g1[q], p);
        p2a += p * p;
    }
}

// ---------------------------------------------------------------------------
// Kernel 1: dense single pass. 1024 blocks (one 16-row band each) x 512
// threads (8 waves: 4 row-quads x 2 column halves). 4 blocks/CU = 32 waves/CU
// at EXACTLY R3's HBM traffic (1024 partial slots, ~3 MB writes) — this
// deconfounds R4's occupancy-vs-traffic experiment.
// No fences/tickets here — kernel-boundary coherence only (R1 lesson).
// ---------------------------------------------------------------------------
__global__ __launch_bounds__(512, 4) void k_main_p(const float* __restrict__ labels,
                                                   const float* __restrict__ images,
                                                   const float* __restrict__ preds,
                                                   int* __restrict__ hist_p,
                                                   int* __restrict__ g0_p,
                                                   float* __restrict__ g1_p,
                                                   float* __restrict__ p2_p,
                                                   int* __restrict__ gt) {
    __shared__ int   s_hist[NBINS];
    __shared__ int   s_g0[NBINS];
    __shared__ float s_g1[NBINS];
    __shared__ float s_thr[NBINS];
    __shared__ float s_red[512];

    const int tid   = threadIdx.x;
    const int lane  = tid & 63;
    const int w     = tid >> 6;             // 0..7
    const int quad  = w >> 1;               // 0..3 (4-row quads)
    const int half  = w & 1;                // 0..1 (256-col halves)
    const int band  = blockIdx.x;           // 0..31 (16-row bands)
    const int b     = blockIdx.y;           // 0..31
    const int slot  = b * 32 + band;
    const int rbase = band * 16 + quad * 4;
    const int cb    = half * 256;
    const int c0    = cb + lane * 4;
    const float* lab = labels + (size_t)b * HW_;
    const float* img = images + (size_t)b * HW_;
    const float* prd = preds  + (size_t)b * HW_;

    if (band == 0 && b == 0 && tid == 0) *gt = 0;   // boundary-ordered reset

    if (tid < 256) {
        s_hist[tid] = 0;
        s_g0[tid]   = 0;
        s_g1[tid]   = 0.0f;
        s_thr[tid]  = (float)tid / 255.0f;
    }
    __syncthreads();

    unsigned mrow[4];
    dilate4c(lab, rbase, cb, lane, mrow);

    float p2a = 0.0f;
#pragma unroll
    for (int r = 0; r < 4; ++r) {
        unsigned m = mrow[r];
        size_t off = (size_t)(rbase + r) * W_ + c0;
        // dense unconditional loads (sparse-load MLP collapse measured earlier)
        float4 iv = *(const float4*)(img + off);
        float4 pv = *(const float4*)(prd + off);
        px_acc(m, 1u, iv.x, pv.x, s_hist, s_g0, s_g1, s_thr, p2a);
        px_acc(m, 2u, iv.y, pv.y, s_hist, s_g0, s_g1, s_thr, p2a);
        px_acc(m, 4u, iv.z, pv.z, s_hist, s_g0, s_g1, s_thr, p2a);
        px_acc(m, 8u, iv.w, pv.w, s_hist, s_g0, s_g1, s_thr, p2a);
    }

    s_red[tid] = p2a;
    __syncthreads();
    // plain stores to this block's own slot (every slot written -> poison-safe)
    if (tid < 256) {
        hist_p[(slot << 8) + tid] = s_hist[tid];
        g0_p  [(slot << 8) + tid] = s_g0[tid];
        g1_p  [(slot << 8) + tid] = s_g1[tid];
    }
    for (int off = 256; off > 0; off >>= 1) {
        if (tid < off) s_red[tid] += s_red[tid + off];
        __syncthreads();
    }
    if (tid == 0) p2_p[slot] = s_red[0];
}

// ---------------------------------------------------------------------------
// Kernel 2: merged search + eval, 32 blocks x 1024 threads.
// R5 restructure: during the argmax region, thread-groups 0-2 compute the
// 254-col argmax (rows 85/85/84 — u64 max is order-free, bit-exact) while
// group 3 concurrently streams the g0/g1/p2 partial reductions into LDS
// (gc/gg computed in the same sequential j order -> bit-identical inputs to
// the f64 suffix trees). Order-sensitive float/f64 phases verbatim, tid<256.
// ---------------------------------------------------------------------------
__global__ __launch_bounds__(1024) void k_tail(const int* __restrict__ hist_p,
                                               const int* __restrict__ g0_p,
                                               const float* __restrict__ g1_p,
                                               const float* __restrict__ p2_p,
                                               float* __restrict__ totf,
                                               float* __restrict__ lp,
                                               int* __restrict__ gt,
                                               float* __restrict__ out) {
    __shared__ float  sA[NBINS];
    __shared__ float  sB[NBINS];
    __shared__ float  sT0[NBINS];
    __shared__ float  sT2[NBINS];
    __shared__ float  sP[NBINS];
    __shared__ float  sQ[NBINS];
    __shared__ float  sGG[NBINS];
    __shared__ float  sP2[32];
    __shared__ int    s_int[1024];
    __shared__ unsigned long long s_pack[1024];
    __shared__ double sD0[256];
    __shared__ double sD1[256];
    __shared__ double s_res[4];

    const int tid = threadIdx.x;
    const int b   = blockIdx.x;
    const float s = 1e-8f;
    const int bin = tid & 255;          // 0..255
    const int grp = tid >> 8;           // 0..3

    // ---- histogram reduce: 32 band-partials -> bin, 4-way split (exact) --
    {
        const int* hp = hist_p + ((b * 32 + grp * 8) << 8) + bin;
        int hp8 = 0;
#pragma unroll
        for (int j = 0; j < 8; ++j) hp8 += hp[j << 8];
        s_int[tid] = hp8;
    }
    __syncthreads();
    int h = 0;
    if (tid < 256)
        h = s_int[tid] + s_int[tid + 256] + s_int[tid + 512] + s_int[tid + 768];
    __syncthreads();                    // all reads done before overwrite
    if (tid < 256) s_int[tid] = h;
    __syncthreads();
    for (int off = 128; off > 0; off >>= 1) {   // exact: integer counts
        if (tid < off) s_int[tid] += s_int[tid + off];
        __syncthreads();
    }
    const float ftot = (float)s_int[0];
    __syncthreads();                    // s_int free for reuse below

    if (tid < 256) {
        float pv = (float)h / ftot;
        sP[tid] = pv;
        sQ[tid] = pv * (float)tid;
    }
    __syncthreads();

    if (tid == 0) {                  // sequential fold == reference cumsum order
        float ch = 0.0f, cm = 0.0f;
#pragma unroll 8
        for (int i = 0; i < NBINS; ++i) {
            ch += sP[i];
            cm += sQ[i];
            sA[i] = ch;
            sB[i] = cm;
        }
    }
    __syncthreads();

    const float tm = sB[NBINS - 1];
    if (tid < NT) {
        float w0 = sA[tid];
        float mean0 = sB[tid] / (w0 + s);
        float d0 = mean0 - tm;
        sT0[tid] = w0 * (d0 * d0);
        float cb = sA[tid];
        float w2 = 1.0f - cb;
        float mean2 = (tm - sB[tid]) / (w2 + s);
        float d2 = mean2 - tm;
        sT2[tid] = w2 * (d2 * d2);
    }
    __syncthreads();

    // ---- OVERLAP region: groups 0-2 argmax  ||  group 3 partial reduces --
    unsigned long long best = 0ull;
    if (grp < 3) {
        if (bin < NT) {
            const float cb  = sA[bin];
            const float m1v = sB[bin];
            const float w2  = 1.0f - cb;
            const float t2v = sT2[bin];
            const int   i0  = grp * 85;
            const int   icnt = (grp == 2) ? 84 : 85;   // 85+85+84 = 254 rows
#pragma unroll 5
            for (int il = 0; il < icnt; ++il) {
                int i = i0 + il;
                float w0 = sA[i];
                float w1 = cb - w0;
                float mean1 = (m1v - sB[i]) / (w1 + s);
                float d1 = mean1 - tm;
                float bv = (sT0[i] + w1 * (d1 * d1)) + t2v;
                bool ok = (w0 > 0.f) && (w1 > 0.f) && (w2 > 0.f);
                bv = ok ? bv : 0.0f;
                unsigned k = (unsigned)(i * NT + bin);
                // bv >= 0: float-bit order == value order; ~k => first-max tie
                unsigned long long pk =
                    ((unsigned long long)__float_as_uint(bv) << 32) | (0xFFFFFFFFu - k);
                best = pk > best ? pk : best;
            }
        }
    } else {
        // group 3: stream g0/g1/p2 partials (independent of argmax).
        // Sequential j order preserved -> gc/gg bit-identical to R3.
        const int*   gp  = g0_p + ((b * 32) << 8) + bin;
        const float* gfp = g1_p + ((b * 32) << 8) + bin;
        int   gc = 0;
        float gg = 0.0f;
#pragma unroll 8
        for (int j = 0; j < 32; ++j) { gc += gp[j << 8]; gg += gfp[j << 8]; }
        s_int[bin] = gc;
        sGG[bin]   = gg;
        if (bin < 32) sP2[bin] = p2_p[b * 32 + bin];
    }
    s_pack[tid] = best;
    __syncthreads();
    for (int off = 512; off > 0; off >>= 1) {
        if (tid < off) {
            unsigned long long o = s_pack[tid + off];
            if (o > s_pack[tid]) s_pack[tid] = o;
        }
        __syncthreads();
    }
    const int am = (int)(0xFFFFFFFFu - (unsigned)(s_pack[0] & 0xFFFFFFFFull));
    const int v  = am / NT + 1;             // im >= t1  <=>  q >= v
    const int wq = am % NT + 1;             // im >= t2  <=>  q >= wq

    // ---- f64 suffix sums S0/S1 at v and wq (validated, 256-tree verbatim) -
    if (tid < 256) {
        sD0[tid] = (tid >= v) ? (double)s_int[tid] : 0.0;
        sD1[tid] = (tid >= v) ? (double)sGG[tid] : 0.0;
    }
    __syncthreads();
    for (int off = 128; off > 0; off >>= 1) {
        if (tid < off) { sD0[tid] += sD0[tid + off]; sD1[tid] += sD1[tid + off]; }
        __syncthreads();
    }
    if (tid == 0) { s_res[0] = sD0[0]; s_res[1] = sD1[0]; }
    __syncthreads();

    if (tid < 256) {
        sD0[tid] = (tid >= wq) ? (double)s_int[tid] : 0.0;
        sD1[tid] = (tid >= wq) ? (double)sGG[tid] : 0.0;
    }
    __syncthreads();
    for (int off = 128; off > 0; off >>= 1) {
        if (tid < off) { sD0[tid] += sD0[tid + off]; sD1[tid] += sD1[tid + off]; }
        __syncthreads();
    }
    if (tid == 0) { s_res[2] = sD0[0]; s_res[3] = sD1[0]; }
    __syncthreads();

    // ---- p2 partial reduce (32 values, 256-tree verbatim) ----------------
    if (tid < 256)
        sD0[tid] = (tid < 32) ? (double)sP2[tid] : 0.0;
    __syncthreads();
    for (int off = 128; off > 0; off >>= 1) {
        if (tid < off) sD0[tid] += sD0[tid + off];
        __syncthreads();
    }

    if (tid == 0) {
        double S0v = s_res[0], S1v = s_res[1];
        double S0w = s_res[2], S1w = s_res[3];
        double c05 = (v <= wq) ? (S0v - S0w) : 0.0;
        double s05 = (v <= wq) ? (S1v - S1w) : 0.0;
        // sum (ci-p)^2 = |A| - 2*S1(A) + 0.25*|B\A| - S1(B\A) + sum p^2
        double sqd = S0w - 2.0 * S1w + 0.25 * c05 - s05 + sD0[0];
        float smv = ftot + 1e-8f;
        float lpv = (smv > 1e-8f) ? (float)sqd / smv : 0.0f;
        __hip_atomic_store(&lp[b], lpv, __ATOMIC_RELEASE, __HIP_MEMORY_SCOPE_AGENT);
        __hip_atomic_store(&totf[b], ftot, __ATOMIC_RELEASE, __HIP_MEMORY_SCOPE_AGENT);
        __threadfence();
        int t = atomicAdd(gt, 1);           // one-shot, no spin (R0-validated)
        if (t == B_ - 1) {                  // last block: all lp[]/totf[] published
            __threadfence();
            float sum = 0.0f;
            int   cnt = 0;
            for (int bb = 0; bb < B_; ++bb) {   // linear order == reference
                float tt = __hip_atomic_load(&totf[bb], __ATOMIC_RELAXED,
                                             __HIP_MEMORY_SCOPE_AGENT);
                float ll = __hip_atomic_load(&lp[bb], __ATOMIC_RELAXED,
                                             __HIP_MEMORY_SCOPE_AGENT);
                if (tt + 1e-8f > 1e-8f) { sum += ll; cnt += 1; }
            }
            out[0] = cnt > 0 ? sum / fmaxf((float)cnt, 1.0f) : 0.0f;
        }
    }
}

extern "C" void kernel_launch(void* const* d_in, const int* in_sizes, int n_in,
                              void* d_out, int out_size, void* d_ws, size_t ws_size,
                              hipStream_t stream) {
    const float* preds  = (const float*)d_in[0];
    const float* labels = (const float*)d_in[1];
    const float* images = (const float*)d_in[2];
    float* out = (float*)d_out;
    char* ws = (char*)d_ws;
    if (ws_size < (size_t)WS_NEED) return;  // harness ws is ~268 MB; never hit

    int*   hist_p = (int*)ws;
    int*   g0_p   = (int*)(ws + OFF_G0);
    float* g1_p   = (float*)(ws + OFF_G1);
    float* p2_p   = (float*)(ws + OFF_P2);
    float* totf   = (float*)(ws + OFF_TOTF);
    float* lp     = (float*)(ws + OFF_LP);
    int*   gt     = (int*)(ws + OFF_GT);

    k_main_p<<<dim3(32, B_), 512, 0, stream>>>(labels, images, preds,
                                               hist_p, g0_p, g1_p, p2_p, gt);
    k_tail<<<B_, 1024, 0, stream>>>(hist_p, g0_p, g1_p, p2_p,
                                    totf, lp, gt, out);
}